// Round 6
// baseline (724.853 us; speedup 1.0000x reference)
//
#include <hip/hip_runtime.h>
#include <hip/hip_bf16.h>

#define N_FEAT 64
#define NBW 9                      // log2(nodes per bucket) = 512
#define SRC_BITS 23                // key = (dstLocal << 23) | src ; src < 2^23

typedef unsigned short u16;

__device__ inline u16 f2bf(float f) {           // RNE f32 -> bf16
    unsigned u = __float_as_uint(f);
    u += 0x7fffu + ((u >> 16) & 1u);
    return (u16)(u >> 16);
}

// ---------------- CSR build: two-level bucket partition ----------------

__global__ __launch_bounds__(256) void coarse_hist(const int* __restrict__ ei, int* bcnt, int E, int NB) {
    __shared__ int h[256];
    int tid = threadIdx.x;
    h[tid] = 0;
    __syncthreads();
    for (int e = blockIdx.x * blockDim.x + tid; e < E; e += gridDim.x * blockDim.x)
        atomicAdd(&h[ei[E + e] >> NBW], 1);
    __syncthreads();
    if (tid < NB && h[tid]) atomicAdd(&bcnt[tid], h[tid]);
}

__global__ __launch_bounds__(256) void coarse_scan(const int* __restrict__ bcnt, int* boff, int* bcur, int NB) {
    __shared__ int wsum[4];
    int tid = threadIdx.x, lane = tid & 63, w = tid >> 6;
    int v = (tid < NB) ? bcnt[tid] : 0;
    int incl = v;
    #pragma unroll
    for (int o = 1; o < 64; o <<= 1) { int t = __shfl_up(incl, o); if (lane >= o) incl += t; }
    if (lane == 63) wsum[w] = incl;
    __syncthreads();
    int add = 0;
    #pragma unroll
    for (int i = 0; i < 4; ++i) if (i < w) add += wsum[i];
    int excl = add + incl - v;
    if (tid < NB) { boff[tid] = excl; bcur[tid] = excl; }
}

__global__ __launch_bounds__(256) void partition(const int* __restrict__ ei, const float* __restrict__ ew,
                                                 int* bcur, int2* __restrict__ ebuf, int E, int NB) {
    constexpr int EPT = 8;
    __shared__ int cnt[256];
    __shared__ int base[256];
    int tid = threadIdx.x;
    cnt[tid] = 0;
    __syncthreads();
    int start = blockIdx.x * (256 * EPT);

    int d[EPT], r[EPT], s[EPT]; float w[EPT];
    #pragma unroll
    for (int i = 0; i < EPT; ++i) {
        int e = start + i * 256 + tid;
        if (e < E) {
            d[i] = ei[E + e];
            s[i] = ei[e];
            w[i] = ew[e];
            r[i] = atomicAdd(&cnt[d[i] >> NBW], 1);
        } else d[i] = -1;
    }
    __syncthreads();
    if (tid < NB && cnt[tid]) base[tid] = atomicAdd(&bcur[tid], cnt[tid]);
    __syncthreads();
    #pragma unroll
    for (int i = 0; i < EPT; ++i) {
        if (d[i] >= 0) {
            int b = d[i] >> NBW;
            int dl = d[i] & ((1 << NBW) - 1);
            int key = (dl << SRC_BITS) | s[i];
            ebuf[base[b] + r[i]] = make_int2(key, __float_as_int(w[i]));
        }
    }
}

__global__ __launch_bounds__(256) void bucket_csr(const int2* __restrict__ ebuf, const int* __restrict__ boff,
                                                  const int* __restrict__ bcnt,
                                                  int2* __restrict__ csr, int* __restrict__ rowp,
                                                  int* __restrict__ cnt, float* __restrict__ dis, int N) {
    __shared__ int   h[512];
    __shared__ float ws[512];
    __shared__ int   off[512];
    __shared__ int   wsum[4];
    int b = blockIdx.x, tid = threadIdx.x;
    int nbase = b << NBW;
    int nn = min(512, N - nbase);
    int beg = boff[b], m = bcnt[b];

    h[tid] = 0; h[tid + 256] = 0;
    ws[tid] = 0.f; ws[tid + 256] = 0.f;
    __syncthreads();

    for (int i = tid; i < m; i += 256) {
        int2 en = ebuf[beg + i];
        int dl = ((unsigned)en.x) >> SRC_BITS;
        atomicAdd(&h[dl], 1);
        atomicAdd(&ws[dl], __int_as_float(en.y));
    }
    __syncthreads();

    int v0 = h[2 * tid], v1 = h[2 * tid + 1];
    int v = v0 + v1;
    int lane = tid & 63, wv = tid >> 6;
    int incl = v;
    #pragma unroll
    for (int o = 1; o < 64; o <<= 1) { int t = __shfl_up(incl, o); if (lane >= o) incl += t; }
    if (lane == 63) wsum[wv] = incl;
    __syncthreads();
    int add = 0;
    #pragma unroll
    for (int i = 0; i < 4; ++i) if (i < wv) add += wsum[i];
    int excl = add + incl - v;
    off[2 * tid] = excl;
    off[2 * tid + 1] = excl + v0;
    __syncthreads();

    for (int l = tid; l < nn; l += 256) {
        rowp[nbase + l] = beg + off[l];
        cnt[nbase + l]  = h[l];
        dis[nbase + l]  = rsqrtf(1.0f + ws[l]);
    }
    __syncthreads();
    h[tid] = 0; h[tid + 256] = 0;
    __syncthreads();

    for (int i = tid; i < m; i += 256) {
        int2 en = ebuf[beg + i];
        unsigned k = (unsigned)en.x;
        int dl  = k >> SRC_BITS;
        int src = k & ((1 << SRC_BITS) - 1);
        int pos = atomicAdd(&h[dl], 1);
        csr[beg + off[dl] + pos] = make_int2(src, en.y);
    }
}

// fold dis[src] into stored weight (csr rebuilt from ebuf each call -> deterministic)
__global__ __launch_bounds__(256) void fold_dis(int2* __restrict__ csr, const float* __restrict__ dis, int E) {
    int i = blockIdx.x * blockDim.x + threadIdx.x;
    if (i < E) {
        int2 en = csr[i];
        en.y = __float_as_int(__int_as_float(en.y) * dis[en.x]);
        csr[i] = en;
    }
}

__global__ __launch_bounds__(256) void pad_w3(const float* __restrict__ W3, float* __restrict__ W3p) {
    int i = blockIdx.x * blockDim.x + threadIdx.x;
    if (i >= 64 * 64) return;
    int k = i >> 6, c = i & 63;
    W3p[i] = (c < 16) ? W3[k * 16 + c] : 0.0f;
}

// ---------------- GEMM: C_bf16[N x OUTW] = A[N x 64] @ W[64 x 64] ----------------

template<int OUTW>
__global__ __launch_bounds__(256) void gemm64(const float* __restrict__ A, const float* __restrict__ W,
                                              u16* __restrict__ C, int N) {
    __shared__ float At[64 * 68];
    __shared__ float Wl[64 * 64];
    int tid = threadIdx.x;
    int r0 = blockIdx.x * 64;

    for (int i = tid * 4; i < 4096; i += 1024) {
        *(float4*)&Wl[i] = *(const float4*)&W[i];
    }
    #pragma unroll
    for (int jj = 0; jj < 4; ++jj) {
        int r = (tid >> 4) + jj * 16;
        int c0 = (tid & 15) * 4;
        float4 v = make_float4(0.f, 0.f, 0.f, 0.f);
        if (r0 + r < N) v = *(const float4*)&A[(size_t)(r0 + r) * 64 + c0];
        At[(c0 + 0) * 68 + r] = v.x;
        At[(c0 + 1) * 68 + r] = v.y;
        At[(c0 + 2) * 68 + r] = v.z;
        At[(c0 + 3) * 68 + r] = v.w;
    }
    __syncthreads();

    int tr = tid >> 4, tc = tid & 15;
    float acc[4][4] = {};
    #pragma unroll
    for (int k = 0; k < 64; ++k) {
        float4 a = *(const float4*)&At[k * 68 + 4 * tr];
        float4 w = *(const float4*)&Wl[k * 64 + 4 * tc];
        float av[4] = {a.x, a.y, a.z, a.w};
        float wv[4] = {w.x, w.y, w.z, w.w};
        #pragma unroll
        for (int i = 0; i < 4; ++i)
            #pragma unroll
            for (int j = 0; j < 4; ++j)
                acc[i][j] = fmaf(av[i], wv[j], acc[i][j]);
    }

    if (4 * tc < OUTW) {
        #pragma unroll
        for (int i = 0; i < 4; ++i) {
            int r = r0 + 4 * tr + i;
            if (r < N) {
                ushort4 v = make_ushort4(f2bf(acc[i][0]), f2bf(acc[i][1]),
                                         f2bf(acc[i][2]), f2bf(acc[i][3]));
                *(ushort4*)&C[(size_t)r * OUTW + 4 * tc] = v;
            }
        }
    }
}

// ---------------- Aggregation (bf16 gathers, 8 bf16 per lane) ----------------
// out[n] = sum_e w_folded(e)*dd * hw[s] + dd^2*hw[n] + b ; w_folded = dis[s]*ew

template<int F, bool RELU, bool DUP>
__global__ __launch_bounds__(256) void aggregate(const u16* __restrict__ hw, const int* __restrict__ rowp,
                                                 const int* __restrict__ cnt, const int2* __restrict__ csr,
                                                 const float* __restrict__ dis,
                                                 const float* __restrict__ bias, float* __restrict__ out,
                                                 float* __restrict__ out2, int N) {
    constexpr int LPR = F / 8;        // lanes per row (8 for F=64, 2 for F=16)
    constexpr int EPB = 64 / LPR;     // edges in flight (8 or 32)

    int wid = (int)((blockIdx.x * blockDim.x + threadIdx.x) >> 6);
    int lane = threadIdx.x & 63;
    if (wid >= N) return;
    int n = wid;
    int g = lane / LPR;               // edge slot
    int t = lane % LPR;               // 8-elem chunk within row
    float dd = dis[n];

    float acc[8] = {};
    if (g == 0) {                     // self loop (weight 1)
        uint4 raw = *(const uint4*)&hw[(size_t)n * F + t * 8];
        float w = dd * dd;
        unsigned uw[4] = {raw.x, raw.y, raw.z, raw.w};
        #pragma unroll
        for (int k = 0; k < 4; ++k) {
            acc[2 * k]     = w * __uint_as_float(uw[k] << 16);
            acc[2 * k + 1] = w * __uint_as_float(uw[k] & 0xffff0000u);
        }
    }

    int beg = rowp[n];
    int c = cnt[n];
    for (int base = 0; base < c; base += 64) {
        int m = min(64, c - base);
        int es = 0; float wv = 0.0f;
        if (lane < m) {
            int2 ent = csr[beg + base + lane];
            es = ent.x;
            wv = __int_as_float(ent.y) * dd;     // dis[s] pre-folded
        }
        for (int j = 0; j < m; j += EPB) {
            int idx = j + g;
            int ic = min(idx, m - 1);
            int s = __shfl(es, ic);              // unconditional shuffles
            float wr = __shfl(wv, ic);
            float w = (idx < m) ? wr : 0.0f;     // mask result only
            uint4 raw = *(const uint4*)&hw[(size_t)s * F + t * 8];
            unsigned uw[4] = {raw.x, raw.y, raw.z, raw.w};
            #pragma unroll
            for (int k = 0; k < 4; ++k) {
                acc[2 * k]     = fmaf(w, __uint_as_float(uw[k] << 16), acc[2 * k]);
                acc[2 * k + 1] = fmaf(w, __uint_as_float(uw[k] & 0xffff0000u), acc[2 * k + 1]);
            }
        }
    }

    #pragma unroll
    for (int off = LPR; off < 64; off <<= 1) {
        #pragma unroll
        for (int k = 0; k < 8; ++k) acc[k] += __shfl_xor(acc[k], off);
    }

    if (g == 0) {
        float4 b0 = *(const float4*)&bias[t * 8];
        float4 b1 = *(const float4*)&bias[t * 8 + 4];
        float4 r0 = make_float4(acc[0] + b0.x, acc[1] + b0.y, acc[2] + b0.z, acc[3] + b0.w);
        float4 r1 = make_float4(acc[4] + b1.x, acc[5] + b1.y, acc[6] + b1.z, acc[7] + b1.w);
        if (RELU) {
            r0.x = fmaxf(r0.x, 0.f); r0.y = fmaxf(r0.y, 0.f);
            r0.z = fmaxf(r0.z, 0.f); r0.w = fmaxf(r0.w, 0.f);
            r1.x = fmaxf(r1.x, 0.f); r1.y = fmaxf(r1.y, 0.f);
            r1.z = fmaxf(r1.z, 0.f); r1.w = fmaxf(r1.w, 0.f);
        }
        *(float4*)&out[(size_t)n * F + t * 8] = r0;
        *(float4*)&out[(size_t)n * F + t * 8 + 4] = r1;
        if (DUP) {
            *(float4*)&out2[(size_t)n * F + t * 8] = r0;
            *(float4*)&out2[(size_t)n * F + t * 8 + 4] = r1;
        }
    }
}

// ---------------- log-softmax over 16 classes ----------------

__global__ __launch_bounds__(256) void logsoftmax16(const float* __restrict__ logits,
                                                    float* __restrict__ out, int N) {
    int g = blockIdx.x * blockDim.x + threadIdx.x;
    int node = g >> 4;
    if (node >= N) return;
    float x = logits[g];
    float m = x;
    #pragma unroll
    for (int o = 1; o < 16; o <<= 1) m = fmaxf(m, __shfl_xor(m, o));
    float e = __expf(x - m);
    float ssum = e;
    #pragma unroll
    for (int o = 1; o < 16; o <<= 1) ssum += __shfl_xor(ssum, o);
    out[g] = x - m - __logf(ssum);
}

// ---------------- launch ----------------

extern "C" void kernel_launch(void* const* d_in, const int* in_sizes, int n_in,
                              void* d_out, int out_size, void* d_ws, size_t ws_size,
                              hipStream_t stream) {
    const float* x   = (const float*)d_in[0];
    const int*   ei  = (const int*)d_in[1];
    const float* ew  = (const float*)d_in[2];
    const float* W1  = (const float*)d_in[3];
    const float* b1  = (const float*)d_in[4];
    const float* W2  = (const float*)d_in[5];
    const float* b2  = (const float*)d_in[6];
    const float* W3  = (const float*)d_in[7];
    const float* b3  = (const float*)d_in[8];
    float* out = (float*)d_out;

    const int N = in_sizes[0] / N_FEAT;      // 100000
    const int E = in_sizes[2];               // 1600000
    const int NB = (N + (1 << NBW) - 1) >> NBW;

    size_t off = 0;
    auto alloc = [&](size_t bytes) {
        void* p = (char*)d_ws + off;
        off += (bytes + 255) & ~(size_t)255;
        return p;
    };
    float* dis     = (float*)alloc((size_t)N * 4);
    int*   cnt     = (int*)alloc((size_t)N * 4);
    int*   rowp    = (int*)alloc((size_t)N * 4);
    int*   bcnt    = (int*)alloc(256 * 4);
    int*   boff    = (int*)alloc(256 * 4);
    int*   bcur    = (int*)alloc(256 * 4);
    int2*  csr     = (int2*)alloc((size_t)E * 8);
    float* bufA    = (float*)alloc((size_t)N * 64 * 4);  // f32 agg output / gemm input
    u16*   hwB     = (u16*)alloc((size_t)N * 64 * 2);    // bf16 gemm output (gather side)
    u16*   hw16    = (u16*)alloc((size_t)N * 16 * 2);    // bf16 layer-3 gemm output
    float* W3p     = (float*)alloc(64 * 64 * 4);
    int2*  ebuf    = (int2*)bufA;            // staging overlays bufA (consumed before layer-1 agg writes it)

    const int TB = 256;

    // CSR build
    hipMemsetAsync(bcnt, 0, 256 * 4, stream);
    coarse_hist<<<512, TB, 0, stream>>>(ei, bcnt, E, NB);
    coarse_scan<<<1, TB, 0, stream>>>(bcnt, boff, bcur, NB);
    partition<<<(E + 2047) / 2048, TB, 0, stream>>>(ei, ew, bcur, ebuf, E, NB);
    bucket_csr<<<NB, TB, 0, stream>>>(ebuf, boff, bcnt, csr, rowp, cnt, dis, N);
    fold_dis<<<(E + TB - 1) / TB, TB, 0, stream>>>(csr, dis, E);
    pad_w3<<<16, TB, 0, stream>>>(W3, W3p);

    int gblk = (N + 63) / 64;
    int ablk = (N * 64 + TB - 1) / TB;

    float* logits = out + (size_t)N * 16;
    float* logits2 = out + (size_t)2 * N * 16;

    // layer 1
    gemm64<64><<<gblk, TB, 0, stream>>>(x, W1, hwB, N);
    aggregate<64, true, false><<<ablk, TB, 0, stream>>>(hwB, rowp, cnt, csr, dis, b1, bufA, nullptr, N);
    // layer 2
    gemm64<64><<<gblk, TB, 0, stream>>>(bufA, W2, hwB, N);
    aggregate<64, true, false><<<ablk, TB, 0, stream>>>(hwB, rowp, cnt, csr, dis, b2, bufA, nullptr, N);
    // layer 3 (store only 16 valid cols, bf16)
    gemm64<16><<<gblk, TB, 0, stream>>>(bufA, W3p, hw16, N);
    aggregate<16, false, true><<<ablk, TB, 0, stream>>>(hw16, rowp, cnt, csr, dis, b3, logits, logits2, N);

    // log-softmax
    int lsblk = (N * 16 + TB - 1) / TB;
    logsoftmax16<<<lsblk, TB, 0, stream>>>(logits, out, N);
}

// Round 7
// 323.184 us; speedup vs baseline: 2.2428x; 2.2428x over previous
//
#include <hip/hip_runtime.h>
#include <hip/hip_bf16.h>

#define N_FEAT 64
#define NBW 9                      // log2(nodes per bucket) = 512
#define SRC_BITS 23                // key = (dstLocal << 23) | src ; src < 2^23

typedef unsigned short u16;

__device__ inline u16 f2bf(float f) {           // RNE f32 -> bf16
    unsigned u = __float_as_uint(f);
    u += 0x7fffu + ((u >> 16) & 1u);
    return (u16)(u >> 16);
}

// ---------------- CSR build: two-level bucket partition ----------------

__global__ __launch_bounds__(256) void coarse_hist(const int* __restrict__ ei, int* bcnt, int E, int NB) {
    __shared__ int h[256];
    int tid = threadIdx.x;
    h[tid] = 0;
    __syncthreads();
    for (int e = blockIdx.x * blockDim.x + tid; e < E; e += gridDim.x * blockDim.x)
        atomicAdd(&h[ei[E + e] >> NBW], 1);
    __syncthreads();
    if (tid < NB && h[tid]) atomicAdd(&bcnt[tid], h[tid]);
}

__global__ __launch_bounds__(256) void coarse_scan(const int* __restrict__ bcnt, int* boff, int* bcur, int NB) {
    __shared__ int wsum[4];
    int tid = threadIdx.x, lane = tid & 63, w = tid >> 6;
    int v = (tid < NB) ? bcnt[tid] : 0;
    int incl = v;
    #pragma unroll
    for (int o = 1; o < 64; o <<= 1) { int t = __shfl_up(incl, o); if (lane >= o) incl += t; }
    if (lane == 63) wsum[w] = incl;
    __syncthreads();
    int add = 0;
    #pragma unroll
    for (int i = 0; i < 4; ++i) if (i < w) add += wsum[i];
    int excl = add + incl - v;
    if (tid < NB) { boff[tid] = excl; bcur[tid] = excl; }
}

__global__ __launch_bounds__(256) void partition(const int* __restrict__ ei, const float* __restrict__ ew,
                                                 int* bcur, int2* __restrict__ ebuf, int E, int NB) {
    constexpr int EPT = 8;
    __shared__ int cnt[256];
    __shared__ int base[256];
    int tid = threadIdx.x;
    cnt[tid] = 0;
    __syncthreads();
    int start = blockIdx.x * (256 * EPT);

    int d[EPT], r[EPT], s[EPT]; float w[EPT];
    #pragma unroll
    for (int i = 0; i < EPT; ++i) {
        int e = start + i * 256 + tid;
        if (e < E) {
            d[i] = ei[E + e];
            s[i] = ei[e];
            w[i] = ew[e];
            r[i] = atomicAdd(&cnt[d[i] >> NBW], 1);
        } else d[i] = -1;
    }
    __syncthreads();
    if (tid < NB && cnt[tid]) base[tid] = atomicAdd(&bcur[tid], cnt[tid]);
    __syncthreads();
    #pragma unroll
    for (int i = 0; i < EPT; ++i) {
        if (d[i] >= 0) {
            int b = d[i] >> NBW;
            int dl = d[i] & ((1 << NBW) - 1);
            int key = (dl << SRC_BITS) | s[i];
            ebuf[base[b] + r[i]] = make_int2(key, __float_as_int(w[i]));
        }
    }
}

__global__ __launch_bounds__(256) void bucket_csr(const int2* __restrict__ ebuf, const int* __restrict__ boff,
                                                  const int* __restrict__ bcnt,
                                                  int2* __restrict__ csr, int* __restrict__ rowp,
                                                  int* __restrict__ cnt, float* __restrict__ dis, int N) {
    __shared__ int   h[512];
    __shared__ float ws[512];
    __shared__ int   off[512];
    __shared__ int   wsum[4];
    int b = blockIdx.x, tid = threadIdx.x;
    int nbase = b << NBW;
    int nn = min(512, N - nbase);
    int beg = boff[b], m = bcnt[b];

    h[tid] = 0; h[tid + 256] = 0;
    ws[tid] = 0.f; ws[tid + 256] = 0.f;
    __syncthreads();

    for (int i = tid; i < m; i += 256) {
        int2 en = ebuf[beg + i];
        int dl = ((unsigned)en.x) >> SRC_BITS;
        atomicAdd(&h[dl], 1);
        atomicAdd(&ws[dl], __int_as_float(en.y));
    }
    __syncthreads();

    int v0 = h[2 * tid], v1 = h[2 * tid + 1];
    int v = v0 + v1;
    int lane = tid & 63, wv = tid >> 6;
    int incl = v;
    #pragma unroll
    for (int o = 1; o < 64; o <<= 1) { int t = __shfl_up(incl, o); if (lane >= o) incl += t; }
    if (lane == 63) wsum[wv] = incl;
    __syncthreads();
    int add = 0;
    #pragma unroll
    for (int i = 0; i < 4; ++i) if (i < wv) add += wsum[i];
    int excl = add + incl - v;
    off[2 * tid] = excl;
    off[2 * tid + 1] = excl + v0;
    __syncthreads();

    for (int l = tid; l < nn; l += 256) {
        rowp[nbase + l] = beg + off[l];
        cnt[nbase + l]  = h[l];
        dis[nbase + l]  = rsqrtf(1.0f + ws[l]);
    }
    __syncthreads();
    h[tid] = 0; h[tid + 256] = 0;
    __syncthreads();

    for (int i = tid; i < m; i += 256) {
        int2 en = ebuf[beg + i];
        unsigned k = (unsigned)en.x;
        int dl  = k >> SRC_BITS;
        int src = k & ((1 << SRC_BITS) - 1);
        int pos = atomicAdd(&h[dl], 1);
        csr[beg + off[dl] + pos] = make_int2(src, en.y);
    }
}

// fold dis[src] into stored weight
__global__ __launch_bounds__(256) void fold_dis(int2* __restrict__ csr, const float* __restrict__ dis, int E) {
    int i = blockIdx.x * blockDim.x + threadIdx.x;
    if (i < E) {
        int2 en = csr[i];
        en.y = __float_as_int(__int_as_float(en.y) * dis[en.x]);
        csr[i] = en;
    }
}

__global__ __launch_bounds__(256) void pad_w3(const float* __restrict__ W3, float* __restrict__ W3p) {
    int i = blockIdx.x * blockDim.x + threadIdx.x;
    if (i >= 64 * 64) return;
    int k = i >> 6, c = i & 63;
    W3p[i] = (c < 16) ? W3[k * 16 + c] : 0.0f;
}

// ---------------- GEMM v2: register-resident, LDS-free ----------------
// C_bf16[N x OUTW] = A[N x 64] @ W[64 x 64]
// Each lane owns W column `lane` in 64 VGPRs (loaded once per wave, amortized
// via grid-stride). Row index is forced wave-uniform (readfirstlane) so the
// A-row reads are uniform -> scalar loads feeding v_fma(sgpr, vgpr, vgpr).
// 4 rows per chunk; no LDS, no shuffles, no __syncthreads.

template<int OUTW>
__global__ __launch_bounds__(256) void gemm_rv(const float* __restrict__ A, const float* __restrict__ W,
                                               u16* __restrict__ C, int N) {
    int lane = threadIdx.x & 63;
    int wid  = (int)((blockIdx.x * blockDim.x + threadIdx.x) >> 6);
    int nw   = (int)((gridDim.x * blockDim.x) >> 6);

    float wcol[64];
    #pragma unroll
    for (int k = 0; k < 64; ++k) wcol[k] = W[k * 64 + lane];

    for (int r0 = wid * 4; r0 < N; r0 += nw * 4) {
        int rb = __builtin_amdgcn_readfirstlane(r0);     // wave-uniform row base
        const float* arow = A + (size_t)rb * 64;         // uniform address
        float acc0 = 0.f, acc1 = 0.f, acc2 = 0.f, acc3 = 0.f;
        for (int kc = 0; kc < 64; kc += 16) {
            #pragma unroll
            for (int k = 0; k < 16; ++k) {
                int kk = kc + k;
                acc0 = fmaf(arow[kk],       wcol[kk], acc0);
                acc1 = fmaf(arow[64 + kk],  wcol[kk], acc1);
                acc2 = fmaf(arow[128 + kk], wcol[kk], acc2);
                acc3 = fmaf(arow[192 + kk], wcol[kk], acc3);
            }
        }
        bool cok = (OUTW == 64) || (lane < OUTW);
        if (cok) {
            if (rb + 0 < N) C[(size_t)(rb + 0) * OUTW + lane] = f2bf(acc0);
            if (rb + 1 < N) C[(size_t)(rb + 1) * OUTW + lane] = f2bf(acc1);
            if (rb + 2 < N) C[(size_t)(rb + 2) * OUTW + lane] = f2bf(acc2);
            if (rb + 3 < N) C[(size_t)(rb + 3) * OUTW + lane] = f2bf(acc3);
        }
    }
}

// ---------------- Aggregation (bf16 gathers, 8 bf16 per lane) ----------------

template<int F, bool RELU, bool DUP>
__global__ __launch_bounds__(256) void aggregate(const u16* __restrict__ hw, const int* __restrict__ rowp,
                                                 const int* __restrict__ cnt, const int2* __restrict__ csr,
                                                 const float* __restrict__ dis,
                                                 const float* __restrict__ bias, float* __restrict__ out,
                                                 float* __restrict__ out2, int N) {
    constexpr int LPR = F / 8;        // lanes per row (8 for F=64, 2 for F=16)
    constexpr int EPB = 64 / LPR;     // edges in flight (8 or 32)

    int wid = (int)((blockIdx.x * blockDim.x + threadIdx.x) >> 6);
    int lane = threadIdx.x & 63;
    if (wid >= N) return;
    int n = wid;
    int g = lane / LPR;
    int t = lane % LPR;
    float dd = dis[n];

    float acc[8] = {};
    if (g == 0) {                     // self loop (weight 1)
        uint4 raw = *(const uint4*)&hw[(size_t)n * F + t * 8];
        float w = dd * dd;
        unsigned uw[4] = {raw.x, raw.y, raw.z, raw.w};
        #pragma unroll
        for (int k = 0; k < 4; ++k) {
            acc[2 * k]     = w * __uint_as_float(uw[k] << 16);
            acc[2 * k + 1] = w * __uint_as_float(uw[k] & 0xffff0000u);
        }
    }

    int beg = rowp[n];
    int c = cnt[n];
    for (int base = 0; base < c; base += 64) {
        int m = min(64, c - base);
        int es = 0; float wv = 0.0f;
        if (lane < m) {
            int2 ent = csr[beg + base + lane];
            es = ent.x;
            wv = __int_as_float(ent.y) * dd;     // dis[s] pre-folded
        }
        for (int j = 0; j < m; j += EPB) {
            int idx = j + g;
            int ic = min(idx, m - 1);
            int s = __shfl(es, ic);              // unconditional shuffles
            float wr = __shfl(wv, ic);
            float w = (idx < m) ? wr : 0.0f;     // mask result only
            uint4 raw = *(const uint4*)&hw[(size_t)s * F + t * 8];
            unsigned uw[4] = {raw.x, raw.y, raw.z, raw.w};
            #pragma unroll
            for (int k = 0; k < 4; ++k) {
                acc[2 * k]     = fmaf(w, __uint_as_float(uw[k] << 16), acc[2 * k]);
                acc[2 * k + 1] = fmaf(w, __uint_as_float(uw[k] & 0xffff0000u), acc[2 * k + 1]);
            }
        }
    }

    #pragma unroll
    for (int off = LPR; off < 64; off <<= 1) {
        #pragma unroll
        for (int k = 0; k < 8; ++k) acc[k] += __shfl_xor(acc[k], off);
    }

    if (g == 0) {
        float4 b0 = *(const float4*)&bias[t * 8];
        float4 b1 = *(const float4*)&bias[t * 8 + 4];
        float4 r0 = make_float4(acc[0] + b0.x, acc[1] + b0.y, acc[2] + b0.z, acc[3] + b0.w);
        float4 r1 = make_float4(acc[4] + b1.x, acc[5] + b1.y, acc[6] + b1.z, acc[7] + b1.w);
        if (RELU) {
            r0.x = fmaxf(r0.x, 0.f); r0.y = fmaxf(r0.y, 0.f);
            r0.z = fmaxf(r0.z, 0.f); r0.w = fmaxf(r0.w, 0.f);
            r1.x = fmaxf(r1.x, 0.f); r1.y = fmaxf(r1.y, 0.f);
            r1.z = fmaxf(r1.z, 0.f); r1.w = fmaxf(r1.w, 0.f);
        }
        *(float4*)&out[(size_t)n * F + t * 8] = r0;
        *(float4*)&out[(size_t)n * F + t * 8 + 4] = r1;
        if (DUP) {
            *(float4*)&out2[(size_t)n * F + t * 8] = r0;
            *(float4*)&out2[(size_t)n * F + t * 8 + 4] = r1;
        }
    }
}

// ---------------- log-softmax over 16 classes ----------------

__global__ __launch_bounds__(256) void logsoftmax16(const float* __restrict__ logits,
                                                    float* __restrict__ out, int N) {
    int g = blockIdx.x * blockDim.x + threadIdx.x;
    int node = g >> 4;
    if (node >= N) return;
    float x = logits[g];
    float m = x;
    #pragma unroll
    for (int o = 1; o < 16; o <<= 1) m = fmaxf(m, __shfl_xor(m, o));
    float e = __expf(x - m);
    float ssum = e;
    #pragma unroll
    for (int o = 1; o < 16; o <<= 1) ssum += __shfl_xor(ssum, o);
    out[g] = x - m - __logf(ssum);
}

// ---------------- launch ----------------

extern "C" void kernel_launch(void* const* d_in, const int* in_sizes, int n_in,
                              void* d_out, int out_size, void* d_ws, size_t ws_size,
                              hipStream_t stream) {
    const float* x   = (const float*)d_in[0];
    const int*   ei  = (const int*)d_in[1];
    const float* ew  = (const float*)d_in[2];
    const float* W1  = (const float*)d_in[3];
    const float* b1  = (const float*)d_in[4];
    const float* W2  = (const float*)d_in[5];
    const float* b2  = (const float*)d_in[6];
    const float* W3  = (const float*)d_in[7];
    const float* b3  = (const float*)d_in[8];
    float* out = (float*)d_out;

    const int N = in_sizes[0] / N_FEAT;      // 100000
    const int E = in_sizes[2];               // 1600000
    const int NB = (N + (1 << NBW) - 1) >> NBW;

    size_t off = 0;
    auto alloc = [&](size_t bytes) {
        void* p = (char*)d_ws + off;
        off += (bytes + 255) & ~(size_t)255;
        return p;
    };
    float* dis     = (float*)alloc((size_t)N * 4);
    int*   cnt     = (int*)alloc((size_t)N * 4);
    int*   rowp    = (int*)alloc((size_t)N * 4);
    int*   bcnt    = (int*)alloc(256 * 4);
    int*   boff    = (int*)alloc(256 * 4);
    int*   bcur    = (int*)alloc(256 * 4);
    int2*  csr     = (int2*)alloc((size_t)E * 8);
    float* bufA    = (float*)alloc((size_t)N * 64 * 4);  // f32 agg output / gemm input
    u16*   hwB     = (u16*)alloc((size_t)N * 64 * 2);    // bf16 gemm output (gather side)
    u16*   hw16    = (u16*)alloc((size_t)N * 16 * 2);    // bf16 layer-3 gemm output
    float* W3p     = (float*)alloc(64 * 64 * 4);
    int2*  ebuf    = (int2*)bufA;            // staging overlays bufA (consumed before layer-1 agg writes it)

    const int TB = 256;

    // CSR build
    hipMemsetAsync(bcnt, 0, 256 * 4, stream);
    coarse_hist<<<512, TB, 0, stream>>>(ei, bcnt, E, NB);
    coarse_scan<<<1, TB, 0, stream>>>(bcnt, boff, bcur, NB);
    partition<<<(E + 2047) / 2048, TB, 0, stream>>>(ei, ew, bcur, ebuf, E, NB);
    bucket_csr<<<NB, TB, 0, stream>>>(ebuf, boff, bcnt, csr, rowp, cnt, dis, N);
    fold_dis<<<(E + TB - 1) / TB, TB, 0, stream>>>(csr, dis, E);
    pad_w3<<<16, TB, 0, stream>>>(W3, W3p);

    const int GB = 512;                       // gemm blocks (grid-stride, W reload amortized)
    int ablk = (N * 64 + TB - 1) / TB;

    float* logits = out + (size_t)N * 16;
    float* logits2 = out + (size_t)2 * N * 16;

    // layer 1
    gemm_rv<64><<<GB, TB, 0, stream>>>(x, W1, hwB, N);
    aggregate<64, true, false><<<ablk, TB, 0, stream>>>(hwB, rowp, cnt, csr, dis, b1, bufA, nullptr, N);
    // layer 2
    gemm_rv<64><<<GB, TB, 0, stream>>>(bufA, W2, hwB, N);
    aggregate<64, true, false><<<ablk, TB, 0, stream>>>(hwB, rowp, cnt, csr, dis, b2, bufA, nullptr, N);
    // layer 3 (store only 16 valid cols, bf16)
    gemm_rv<16><<<GB, TB, 0, stream>>>(bufA, W3p, hw16, N);
    aggregate<16, false, true><<<ablk, TB, 0, stream>>>(hw16, rowp, cnt, csr, dis, b3, logits, logits2, N);

    // log-softmax
    int lsblk = (N * 16 + TB - 1) / TB;
    logsoftmax16<<<lsblk, TB, 0, stream>>>(logits, out, N);
}